// Round 1
// baseline (657.570 us; speedup 1.0000x reference)
//
#include <hip/hip_runtime.h>

#define DIN  32
#define DH   64
#define DOUT 16

// ---------------------------------------------------------------- degree ----
__global__ void k_init_deg(float* __restrict__ deg, int N) {
    int i = blockIdx.x * blockDim.x + threadIdx.x;
    if (i < N) deg[i] = 1.0f;                 // self-loop contributes 1
}

__global__ void k_count_deg(const int* __restrict__ dst, float* __restrict__ deg, int E) {
    int e = blockIdx.x * blockDim.x + threadIdx.x;
    if (e < E) atomicAdd(&deg[dst[e]], 1.0f); // exact for counts < 2^24
}

__global__ void k_dinv(float* __restrict__ deg, int N) {
    int i = blockIdx.x * blockDim.x + threadIdx.x;
    if (i < N) deg[i] = rsqrtf(deg[i]);
}

// ------------------------------------------------- layer 1: h1g = dinv*(x@W1)
// block = 256 threads = 4 nodes x 64 feature-threads
__global__ void k_gemm1(const float* __restrict__ x, const float* __restrict__ W1,
                        const float* __restrict__ dinv, float* __restrict__ h1g, int N) {
    __shared__ float Ws[DIN * DH];   // 8 KB
    __shared__ float xs[4][DIN];
    int tid = threadIdx.x;
    for (int t = tid; t < DIN * DH; t += 256) Ws[t] = W1[t];
    int g = tid >> 6, k = tid & 63;
    int node = blockIdx.x * 4 + g;
    if (k < DIN && node < N) xs[g][k] = x[(size_t)node * DIN + k];
    __syncthreads();
    if (node < N) {
        float acc = 0.f;
#pragma unroll
        for (int d = 0; d < DIN; ++d) acc += xs[g][d] * Ws[d * DH + k];
        h1g[(size_t)node * DH + k] = dinv[node] * acc;
    }
}

// ------------------------------------------- scatter1: acc1[dst] += h1g[src]
// one wave (64 lanes) per edge; lane k handles feature k (256B coalesced)
__global__ void k_scatter1(const int* __restrict__ src, const int* __restrict__ dst,
                           const float* __restrict__ h1g, float* __restrict__ acc1, int E) {
    int gt   = blockIdx.x * blockDim.x + threadIdx.x;
    int e    = gt >> 6;
    int lane = threadIdx.x & 63;
    if (e < E) {
        int s = src[e], d = dst[e];
        float v = h1g[(size_t)s * DH + lane];
        atomicAdd(&acc1[(size_t)d * DH + lane], v);
    }
}

// ---------- finalize1 + layer2 matmul: g2 = dinv * (relu(dinv*(acc1+g1)+b1) @ W2)
// block = 256 threads = 4 nodes x 64
__global__ void k_fin1_gemm2(const float* __restrict__ acc1, const float* __restrict__ h1g,
                             const float* __restrict__ dinv, const float* __restrict__ b1,
                             const float* __restrict__ W2, float* __restrict__ g2, int N) {
    __shared__ float Ws[DH * DOUT]; // 4 KB
    __shared__ float ts[4][DH];
    int tid = threadIdx.x;
    for (int t = tid; t < DH * DOUT; t += 256) Ws[t] = W2[t];
    int g = tid >> 6, k = tid & 63;
    int node = blockIdx.x * 4 + g;
    float di = 0.f;
    if (node < N) {
        di = dinv[node];
        size_t idx = (size_t)node * DH + k;
        float v = di * (acc1[idx] + h1g[idx]) + b1[k]; // + self-loop term g1_i
        ts[g][k] = fmaxf(v, 0.f);                      // relu
    }
    __syncthreads();
    if (node < N && k < DOUT) {
        float acc = 0.f;
#pragma unroll
        for (int d = 0; d < DH; ++d) acc += ts[g][d] * Ws[d * DOUT + k];
        g2[(size_t)node * DOUT + k] = di * acc;
    }
}

// ------------------------------------------- scatter2: acc2[dst] += g2[src]
// one thread per (edge, feature): 16 consecutive threads share an edge
__global__ void k_scatter2(const int* __restrict__ src, const int* __restrict__ dst,
                           const float* __restrict__ g2, float* __restrict__ acc2, int E) {
    int t = blockIdx.x * blockDim.x + threadIdx.x;
    int e = t >> 4, k = t & 15;
    if (e < E) {
        int s = src[e], d = dst[e];
        atomicAdd(&acc2[(size_t)d * DOUT + k], g2[(size_t)s * DOUT + k]);
    }
}

// ------------------------------------------------------------- finalize2 ----
__global__ void k_fin2(const float* __restrict__ acc2, const float* __restrict__ g2,
                       const float* __restrict__ dinv, const float* __restrict__ b2,
                       float* __restrict__ out, int N) {
    int t = blockIdx.x * blockDim.x + threadIdx.x;
    if (t < N * DOUT) {
        int i = t >> 4, k = t & 15;
        out[t] = dinv[i] * (acc2[t] + g2[t]) + b2[k]; // + self-loop term g2_i
    }
}

// ----------------------------------------------------------------------------
extern "C" void kernel_launch(void* const* d_in, const int* in_sizes, int n_in,
                              void* d_out, int out_size, void* d_ws, size_t ws_size,
                              hipStream_t stream) {
    const float* x  = (const float*)d_in[0];
    const int*   ei = (const int*)  d_in[1];
    const float* W1 = (const float*)d_in[2];
    const float* b1 = (const float*)d_in[3];
    const float* W2 = (const float*)d_in[4];
    const float* b2 = (const float*)d_in[5];
    float* out = (float*)d_out;

    int N = in_sizes[0] / DIN;
    int E = in_sizes[1] / 2;
    const int* src = ei;
    const int* dst = ei + E;

    // workspace layout (floats): dinv[N] | h1g[N*64] | acc1[N*64] | g2[N*16] | acc2[N*16]
    float* ws   = (float*)d_ws;
    float* dinv = ws;
    float* h1g  = dinv + N;
    float* acc1 = h1g  + (size_t)N * DH;
    float* g2   = acc1 + (size_t)N * DH;
    float* acc2 = g2   + (size_t)N * DOUT;

    hipMemsetAsync(acc1, 0, (size_t)N * DH   * sizeof(float), stream);
    hipMemsetAsync(acc2, 0, (size_t)N * DOUT * sizeof(float), stream);

    k_init_deg <<<(N + 255) / 256, 256, 0, stream>>>(dinv, N);
    k_count_deg<<<(E + 255) / 256, 256, 0, stream>>>(dst, dinv, E);
    k_dinv     <<<(N + 255) / 256, 256, 0, stream>>>(dinv, N);

    k_gemm1<<<(N + 3) / 4, 256, 0, stream>>>(x, W1, dinv, h1g, N);

    {   // wave per edge: E*64 threads
        long long threads = (long long)E * 64;
        int blocks = (int)((threads + 255) / 256);
        k_scatter1<<<blocks, 256, 0, stream>>>(src, dst, h1g, acc1, E);
    }

    k_fin1_gemm2<<<(N + 3) / 4, 256, 0, stream>>>(acc1, h1g, dinv, b1, W2, g2, N);

    {   // thread per (edge, feature): E*16 threads
        long long threads = (long long)E * 16;
        int blocks = (int)((threads + 255) / 256);
        k_scatter2<<<blocks, 256, 0, stream>>>(src, dst, g2, acc2, E);
    }

    k_fin2<<<(N * DOUT + 255) / 256, 256, 0, stream>>>(acc2, g2, dinv, b2, out, N);
}

// Round 2
// 523.539 us; speedup vs baseline: 1.2560x; 1.2560x over previous
//
#include <hip/hip_runtime.h>

#define DIN  32
#define DH   64
#define DOUT 16
#define SCAN_BLK 1024   // elements per scan block; supports N <= 262144

// ------------------------------------------------------------ degree count --
__global__ void k_count_deg(const int* __restrict__ dst, int* __restrict__ deg, int E) {
    int e = blockIdx.x * blockDim.x + threadIdx.x;
    if (e < E) atomicAdd(&deg[dst[e]], 1);
}

// ------------------------------------------------- scan stage 1: per-block --
// 256 threads x 4 elements; exclusive scan within block + block total
__global__ void k_scan1(const int* __restrict__ deg, int* __restrict__ partial,
                        int* __restrict__ blockSums, int N) {
    __shared__ int s[256];
    int tid  = threadIdx.x;
    int base = blockIdx.x * SCAN_BLK + tid * 4;
    int v0 = (base + 0 < N) ? deg[base + 0] : 0;
    int v1 = (base + 1 < N) ? deg[base + 1] : 0;
    int v2 = (base + 2 < N) ? deg[base + 2] : 0;
    int v3 = (base + 3 < N) ? deg[base + 3] : 0;
    int tot = v0 + v1 + v2 + v3;
    s[tid] = tot;
    __syncthreads();
    for (int off = 1; off < 256; off <<= 1) {
        int t = (tid >= off) ? s[tid - off] : 0;
        __syncthreads();
        s[tid] += t;
        __syncthreads();
    }
    int excl = s[tid] - tot;   // exclusive prefix of this thread's chunk
    if (base + 0 < N) partial[base + 0] = excl;
    if (base + 1 < N) partial[base + 1] = excl + v0;
    if (base + 2 < N) partial[base + 2] = excl + v0 + v1;
    if (base + 3 < N) partial[base + 3] = excl + v0 + v1 + v2;
    if (tid == 255) blockSums[blockIdx.x] = s[255];
}

// ------------------------------------ scan stage 2: scan block sums (1 blk) --
__global__ void k_scan2(int* __restrict__ blockSums, int* __restrict__ blockOff, int NB) {
    __shared__ int s[256];
    int tid = threadIdx.x;
    int v = (tid < NB) ? blockSums[tid] : 0;
    s[tid] = v;
    __syncthreads();
    for (int off = 1; off < 256; off <<= 1) {
        int t = (tid >= off) ? s[tid - off] : 0;
        __syncthreads();
        s[tid] += t;
        __syncthreads();
    }
    if (tid < NB) blockOff[tid] = s[tid] - v; // exclusive
}

// ------- scan stage 3: rowStart = partial+blockOff; cursor=rowStart; dinv ---
__global__ void k_scan3(const int* __restrict__ partial, const int* __restrict__ blockOff,
                        const int* __restrict__ deg, int* __restrict__ rowStart,
                        int* __restrict__ cursor, float* __restrict__ dinv, int N) {
    int i = blockIdx.x * blockDim.x + threadIdx.x;
    if (i < N) {
        int rs = partial[i] + blockOff[i / SCAN_BLK];
        rowStart[i] = rs;
        cursor[i]   = rs;
        dinv[i]     = rsqrtf((float)deg[i] + 1.0f); // +1 self-loop
    }
}

// ------------------------------------------------- CSR fill: bucket by dst --
__global__ void k_fill(const int* __restrict__ src, const int* __restrict__ dst,
                       int* __restrict__ cursor, int* __restrict__ edgeSrc, int E) {
    int e = blockIdx.x * blockDim.x + threadIdx.x;
    if (e < E) {
        int pos = atomicAdd(&cursor[dst[e]], 1);
        edgeSrc[pos] = src[e];
    }
}

// ------------------------------------------------- layer 1: h1g = dinv*(x@W1)
__global__ void k_gemm1(const float* __restrict__ x, const float* __restrict__ W1,
                        const float* __restrict__ dinv, float* __restrict__ h1g, int N) {
    __shared__ float Ws[DIN * DH];   // 8 KB
    __shared__ float xs[4][DIN];
    int tid = threadIdx.x;
    for (int t = tid; t < DIN * DH; t += 256) Ws[t] = W1[t];
    int g = tid >> 6, k = tid & 63;
    int node = blockIdx.x * 4 + g;
    if (k < DIN && node < N) xs[g][k] = x[(size_t)node * DIN + k];
    __syncthreads();
    if (node < N) {
        float acc = 0.f;
#pragma unroll
        for (int d = 0; d < DIN; ++d) acc += xs[g][d] * Ws[d * DH + k];
        h1g[(size_t)node * DH + k] = dinv[node] * acc;
    }
}

// -------- layer-1 aggregate (gather-side, no atomics) + relu + GEMM2 fused --
// wave per node: lane k holds feature k of the running sum
__global__ void k_agg1_gemm2(const int* __restrict__ rowStart, const int* __restrict__ deg,
                             const int* __restrict__ edgeSrc, const float* __restrict__ h1g,
                             const float* __restrict__ dinv, const float* __restrict__ b1,
                             const float* __restrict__ W2, float* __restrict__ g2, int N) {
    __shared__ float Ws[DH * DOUT]; // 4 KB
    __shared__ float ts[4][DH];
    int tid = threadIdx.x;
    for (int t = tid; t < DH * DOUT; t += 256) Ws[t] = W2[t];
    int w = tid >> 6, lane = tid & 63;
    int node = blockIdx.x * 4 + w;
    float di = 0.f;
    if (node < N) {
        float acc = h1g[(size_t)node * DH + lane];        // self-loop term
        int s = rowStart[node], c = deg[node];
        for (int t = 0; t < c; ++t) {
            int j = edgeSrc[s + t];                        // wave-uniform
            acc += h1g[(size_t)j * DH + lane];             // 256B coalesced gather
        }
        di = dinv[node];
        ts[w][lane] = fmaxf(di * acc + b1[lane], 0.f);     // relu(dinv*sum + b1)
    }
    __syncthreads();
    if (node < N && lane < DOUT) {
        float acc = 0.f;
#pragma unroll
        for (int d = 0; d < DH; ++d) acc += ts[w][d] * Ws[d * DOUT + lane];
        g2[(size_t)node * DOUT + lane] = di * acc;         // pre-scale by dinv_i
    }
}

// ------------- layer-2 aggregate (gather-side) + bias -> out, fused finalize
// 16 lanes per node, 16 nodes per 256-block
__global__ void k_agg2(const int* __restrict__ rowStart, const int* __restrict__ deg,
                       const int* __restrict__ edgeSrc, const float* __restrict__ g2,
                       const float* __restrict__ dinv, const float* __restrict__ b2,
                       float* __restrict__ out, int N) {
    int tid = threadIdx.x;
    int nb = tid >> 4, k = tid & 15;
    int node = blockIdx.x * 16 + nb;
    if (node < N) {
        float acc = g2[(size_t)node * DOUT + k];           // self-loop term
        int s = rowStart[node], c = deg[node];
        for (int t = 0; t < c; ++t) {
            int j = edgeSrc[s + t];
            acc += g2[(size_t)j * DOUT + k];               // 64B gather per group
        }
        out[(size_t)node * DOUT + k] = dinv[node] * acc + b2[k];
    }
}

// ----------------------------------------------------------------------------
extern "C" void kernel_launch(void* const* d_in, const int* in_sizes, int n_in,
                              void* d_out, int out_size, void* d_ws, size_t ws_size,
                              hipStream_t stream) {
    const float* x  = (const float*)d_in[0];
    const int*   ei = (const int*)  d_in[1];
    const float* W1 = (const float*)d_in[2];
    const float* b1 = (const float*)d_in[3];
    const float* W2 = (const float*)d_in[4];
    const float* b2 = (const float*)d_in[5];
    float* out = (float*)d_out;

    int N = in_sizes[0] / DIN;
    int E = in_sizes[1] / 2;
    const int* src = ei;
    const int* dst = ei + E;
    int NB = (N + SCAN_BLK - 1) / SCAN_BLK;   // <= 256 for N <= 262144

    // workspace layout (4B units):
    // deg[N] | partial[N] | rowStart[N] | cursor[N] | blockSums[256] | blockOff[256]
    // | dinv[N] | edgeSrc[E] | h1g[N*64] | g2[N*16]
    char* p = (char*)d_ws;
    int*   deg       = (int*)p;               p += (size_t)N * 4;
    int*   partial   = (int*)p;               p += (size_t)N * 4;
    int*   rowStart  = (int*)p;               p += (size_t)N * 4;
    int*   cursor    = (int*)p;               p += (size_t)N * 4;
    int*   blockSums = (int*)p;               p += 256 * 4;
    int*   blockOff  = (int*)p;               p += 256 * 4;
    float* dinv      = (float*)p;             p += (size_t)N * 4;
    int*   edgeSrc   = (int*)p;               p += (size_t)E * 4;
    float* h1g       = (float*)p;             p += (size_t)N * DH * 4;
    float* g2        = (float*)p;             p += (size_t)N * DOUT * 4;

    hipMemsetAsync(deg, 0, (size_t)N * 4, stream);

    k_count_deg<<<(E + 255) / 256, 256, 0, stream>>>(dst, deg, E);
    k_scan1<<<NB, 256, 0, stream>>>(deg, partial, blockSums, N);
    k_scan2<<<1, 256, 0, stream>>>(blockSums, blockOff, NB);
    k_scan3<<<(N + 255) / 256, 256, 0, stream>>>(partial, blockOff, deg,
                                                 rowStart, cursor, dinv, N);
    k_fill<<<(E + 255) / 256, 256, 0, stream>>>(src, dst, cursor, edgeSrc, E);

    k_gemm1<<<(N + 3) / 4, 256, 0, stream>>>(x, W1, dinv, h1g, N);
    k_agg1_gemm2<<<(N + 3) / 4, 256, 0, stream>>>(rowStart, deg, edgeSrc, h1g,
                                                  dinv, b1, W2, g2, N);
    k_agg2<<<(N + 15) / 16, 256, 0, stream>>>(rowStart, deg, edgeSrc, g2,
                                              dinv, b2, out, N);
}

// Round 4
// 425.546 us; speedup vs baseline: 1.5452x; 1.2303x over previous
//
#include <hip/hip_runtime.h>

#define DIN  32
#define DH   64
#define DOUT 16
#define SCAN_BLK 1024   // elements per scan block; supports N <= 262144

// ------------------------------------------------------------ degree count --
__global__ void k_count_deg(const int* __restrict__ dst, int* __restrict__ deg, int E) {
    int e = blockIdx.x * blockDim.x + threadIdx.x;
    if (e < E) atomicAdd(&deg[dst[e]], 1);
}

// ------------------------------------------------- scan stage 1: per-block --
__global__ void k_scan1(const int* __restrict__ deg, int* __restrict__ partial,
                        int* __restrict__ blockSums, int N) {
    __shared__ int s[256];
    int tid  = threadIdx.x;
    int base = blockIdx.x * SCAN_BLK + tid * 4;
    int v0 = (base + 0 < N) ? deg[base + 0] : 0;
    int v1 = (base + 1 < N) ? deg[base + 1] : 0;
    int v2 = (base + 2 < N) ? deg[base + 2] : 0;
    int v3 = (base + 3 < N) ? deg[base + 3] : 0;
    int tot = v0 + v1 + v2 + v3;
    s[tid] = tot;
    __syncthreads();
    for (int off = 1; off < 256; off <<= 1) {
        int t = (tid >= off) ? s[tid - off] : 0;
        __syncthreads();
        s[tid] += t;
        __syncthreads();
    }
    int excl = s[tid] - tot;
    if (base + 0 < N) partial[base + 0] = excl;
    if (base + 1 < N) partial[base + 1] = excl + v0;
    if (base + 2 < N) partial[base + 2] = excl + v0 + v1;
    if (base + 3 < N) partial[base + 3] = excl + v0 + v1 + v2;
    if (tid == 255) blockSums[blockIdx.x] = s[255];
}

// ------------------------------------ scan stage 2: scan block sums (1 blk) --
__global__ void k_scan2(int* __restrict__ blockSums, int* __restrict__ blockOff, int NB) {
    __shared__ int s[256];
    int tid = threadIdx.x;
    int v = (tid < NB) ? blockSums[tid] : 0;
    s[tid] = v;
    __syncthreads();
    for (int off = 1; off < 256; off <<= 1) {
        int t = (tid >= off) ? s[tid - off] : 0;
        __syncthreads();
        s[tid] += t;
        __syncthreads();
    }
    if (tid < NB) blockOff[tid] = s[tid] - v;
}

// ------- scan stage 3: rowStart = partial+blockOff; cursor=rowStart; dinv ---
__global__ void k_scan3(const int* __restrict__ partial, const int* __restrict__ blockOff,
                        const int* __restrict__ deg, int* __restrict__ rowStart,
                        int* __restrict__ cursor, float* __restrict__ dinv, int N) {
    int i = blockIdx.x * blockDim.x + threadIdx.x;
    if (i < N) {
        int rs = partial[i] + blockOff[i / SCAN_BLK];
        rowStart[i] = rs;
        cursor[i]   = rs;
        dinv[i]     = rsqrtf((float)deg[i] + 1.0f); // +1 self-loop
    }
}

// ------------------------------------------------- CSR fill: bucket by dst --
__global__ void k_fill(const int* __restrict__ src, const int* __restrict__ dst,
                       int* __restrict__ cursor, int* __restrict__ edgeSrc, int E) {
    int e = blockIdx.x * blockDim.x + threadIdx.x;
    if (e < E) {
        int pos = atomicAdd(&cursor[dst[e]], 1);
        edgeSrc[pos] = src[e];
    }
}

// ---------------------------------------------------- xg = dinv[i] * x[i,:] --
__global__ void k_xg(const float* __restrict__ x, const float* __restrict__ dinv,
                     float* __restrict__ xg, int N) {
    int t = blockIdx.x * blockDim.x + threadIdx.x;
    if (t < N * DIN) xg[t] = dinv[t >> 5] * x[t];
}

// ---- aggregate in input space + GEMM1 + relu + GEMM2, all fused -------------
// wave per node. lane = half*32 + f: half = edge parity, f = input feature.
__global__ void k_agg1_gemm2(const int* __restrict__ rowStart, const int* __restrict__ deg,
                             const int* __restrict__ edgeSrc, const float* __restrict__ xg,
                             const float* __restrict__ dinv, const float* __restrict__ b1,
                             const float* __restrict__ W1, const float* __restrict__ W2,
                             float* __restrict__ g2, int N) {
    __shared__ float W1s[DIN * DH];   // 8 KB
    __shared__ float W2s[DH * DOUT];  // 4 KB
    __shared__ float hs[4][DH];
    int tid = threadIdx.x;
    for (int t = tid; t < DIN * DH; t += 256) W1s[t] = W1[t];
    for (int t = tid; t < DH * DOUT; t += 256) W2s[t] = W2[t];
    __syncthreads();

    int w = tid >> 6, lane = tid & 63;
    int f = lane & 31, half = lane >> 5;
    int node = blockIdx.x * 4 + w;   // wave-uniform

    float h = 0.f, di = 0.f;
    if (node < N) {
        di = dinv[node];
        int s = rowStart[node], c = deg[node];
        float a0 = 0.f, a1 = 0.f, a2 = 0.f, a3 = 0.f;
        int t = 0;
        for (; t + 8 <= c; t += 8) {           // 8 edges/iter, 4 gathers in flight
            int j0 = edgeSrc[s + t + 0 + half];
            int j1 = edgeSrc[s + t + 2 + half];
            int j2 = edgeSrc[s + t + 4 + half];
            int j3 = edgeSrc[s + t + 6 + half];
            a0 += xg[(size_t)j0 * DIN + f];
            a1 += xg[(size_t)j1 * DIN + f];
            a2 += xg[(size_t)j2 * DIN + f];
            a3 += xg[(size_t)j3 * DIN + f];
        }
        // predicated tail: up to 8 edges, all independent
        if (t + 0 + half < c) { int j = edgeSrc[s + t + 0 + half]; a0 += xg[(size_t)j * DIN + f]; }
        if (t + 2 + half < c) { int j = edgeSrc[s + t + 2 + half]; a1 += xg[(size_t)j * DIN + f]; }
        if (t + 4 + half < c) { int j = edgeSrc[s + t + 4 + half]; a2 += xg[(size_t)j * DIN + f]; }
        if (t + 6 + half < c) { int j = edgeSrc[s + t + 6 + half]; a3 += xg[(size_t)j * DIN + f]; }

        float acc = (a0 + a1) + (a2 + a3);
        acc += __shfl_xor(acc, 32);                 // fold edge-parity halves
        acc += xg[(size_t)node * DIN + f];          // self-loop: dinv_i * x_i
        // acc now = s_i[f] in every lane (dup across halves)

        // GEMM1 via shfl broadcast: lane k computes h1[k], k = lane (0..63)
        float dot = 0.f;
#pragma unroll
        for (int d = 0; d < DIN; ++d) {
            float sv = __shfl(acc, d);
            dot += sv * W1s[d * DH + lane];
        }
        h = fmaxf(di * dot + b1[lane], 0.f);        // relu(dinv_i*(s@W1)+b1)
    }
    hs[w][lane] = h;
    __syncthreads();

    if (node < N && lane < DOUT) {                  // GEMM2: g2 = dinv_i*(h1@W2)
        float dot = 0.f;
#pragma unroll
        for (int d = 0; d < DH; ++d) dot += hs[w][d] * W2s[d * DOUT + lane];
        g2[(size_t)node * DOUT + lane] = di * dot;
    }
}

// ---- layer-2 aggregate + finalize -------------------------------------------
// wave per node. lane = u*16 + k: u = edge slot (0..3), k = output feature.
__global__ void k_agg2(const int* __restrict__ rowStart, const int* __restrict__ deg,
                       const int* __restrict__ edgeSrc, const float* __restrict__ g2,
                       const float* __restrict__ dinv, const float* __restrict__ b2,
                       float* __restrict__ out, int N) {
    int tid = threadIdx.x;
    int w = tid >> 6, lane = tid & 63;
    int u = lane >> 4, k = lane & 15;
    int node = blockIdx.x * 4 + w;   // wave-uniform
    if (node >= N) return;

    int s = rowStart[node], c = deg[node];
    float a0 = 0.f, a1 = 0.f;
    int t = 0;
    for (; t + 8 <= c; t += 8) {               // 8 edges/iter, 2 gathers in flight
        int j0 = edgeSrc[s + t + u];
        int j1 = edgeSrc[s + t + 4 + u];
        a0 += g2[(size_t)j0 * DOUT + k];
        a1 += g2[(size_t)j1 * DOUT + k];
    }
    if (t + u     < c) { int j = edgeSrc[s + t + u];     a0 += g2[(size_t)j * DOUT + k]; }
    if (t + 4 + u < c) { int j = edgeSrc[s + t + 4 + u]; a1 += g2[(size_t)j * DOUT + k]; }

    float acc = a0 + a1;
    acc += __shfl_xor(acc, 16);                // fold 4 edge slots
    acc += __shfl_xor(acc, 32);
    acc += g2[(size_t)node * DOUT + k];        // self-loop
    if (lane < DOUT)
        out[(size_t)node * DOUT + k] = dinv[node] * acc + b2[k];
}

// ----------------------------------------------------------------------------
extern "C" void kernel_launch(void* const* d_in, const int* in_sizes, int n_in,
                              void* d_out, int out_size, void* d_ws, size_t ws_size,
                              hipStream_t stream) {
    const float* x  = (const float*)d_in[0];
    const int*   ei = (const int*)  d_in[1];
    const float* W1 = (const float*)d_in[2];
    const float* b1 = (const float*)d_in[3];
    const float* W2 = (const float*)d_in[4];
    const float* b2 = (const float*)d_in[5];
    float* out = (float*)d_out;

    int N = in_sizes[0] / DIN;
    int E = in_sizes[1] / 2;
    const int* src = ei;
    const int* dst = ei + E;
    int NB = (N + SCAN_BLK - 1) / SCAN_BLK;

    // workspace layout (4B units):
    char* p = (char*)d_ws;
    int*   deg       = (int*)p;   p += (size_t)N * 4;
    int*   partial   = (int*)p;   p += (size_t)N * 4;
    int*   rowStart  = (int*)p;   p += (size_t)N * 4;
    int*   cursor    = (int*)p;   p += (size_t)N * 4;
    int*   blockSums = (int*)p;   p += 256 * 4;
    int*   blockOff  = (int*)p;   p += 256 * 4;
    float* dinv      = (float*)p; p += (size_t)N * 4;
    int*   edgeSrc   = (int*)p;   p += (size_t)E * 4;
    float* xg        = (float*)p; p += (size_t)N * DIN * 4;
    float* g2        = (float*)p; p += (size_t)N * DOUT * 4;

    hipMemsetAsync(deg, 0, (size_t)N * 4, stream);

    k_count_deg<<<(E + 255) / 256, 256, 0, stream>>>(dst, deg, E);
    k_scan1<<<NB, 256, 0, stream>>>(deg, partial, blockSums, N);
    k_scan2<<<1, 256, 0, stream>>>(blockSums, blockOff, NB);
    k_scan3<<<(N + 255) / 256, 256, 0, stream>>>(partial, blockOff, deg,
                                                 rowStart, cursor, dinv, N);
    k_fill<<<(E + 255) / 256, 256, 0, stream>>>(src, dst, cursor, edgeSrc, E);

    k_xg<<<((size_t)N * DIN + 255) / 256, 256, 0, stream>>>(x, dinv, xg, N);
    k_agg1_gemm2<<<(N + 3) / 4, 256, 0, stream>>>(rowStart, deg, edgeSrc, xg,
                                                  dinv, b1, W1, W2, g2, N);
    k_agg2<<<(N + 3) / 4, 256, 0, stream>>>(rowStart, deg, edgeSrc, g2,
                                            dinv, b2, out, N);
}

// Round 5
// 389.462 us; speedup vs baseline: 1.6884x; 1.0927x over previous
//
#include <hip/hip_runtime.h>

#define DIN  32
#define DH   64
#define DOUT 16
#define SCAN_BLK 1024   // elements per scan block; supports N <= 262144
#define NXCD 8

// ------------------------------------------------------------ degree count --
__global__ void k_count_deg(const int* __restrict__ dst, int* __restrict__ deg, int E) {
    int e = blockIdx.x * blockDim.x + threadIdx.x;
    if (e < E) atomicAdd(&deg[dst[e]], 1);
}

// ------------------------------------------------- scan stage 1: per-block --
__global__ void k_scan1(const int* __restrict__ deg, int* __restrict__ partial,
                        int* __restrict__ blockSums, int N) {
    __shared__ int s[256];
    int tid  = threadIdx.x;
    int base = blockIdx.x * SCAN_BLK + tid * 4;
    int v0 = (base + 0 < N) ? deg[base + 0] : 0;
    int v1 = (base + 1 < N) ? deg[base + 1] : 0;
    int v2 = (base + 2 < N) ? deg[base + 2] : 0;
    int v3 = (base + 3 < N) ? deg[base + 3] : 0;
    int tot = v0 + v1 + v2 + v3;
    s[tid] = tot;
    __syncthreads();
    for (int off = 1; off < 256; off <<= 1) {
        int t = (tid >= off) ? s[tid - off] : 0;
        __syncthreads();
        s[tid] += t;
        __syncthreads();
    }
    int excl = s[tid] - tot;
    if (base + 0 < N) partial[base + 0] = excl;
    if (base + 1 < N) partial[base + 1] = excl + v0;
    if (base + 2 < N) partial[base + 2] = excl + v0 + v1;
    if (base + 3 < N) partial[base + 3] = excl + v0 + v1 + v2;
    if (tid == 255) blockSums[blockIdx.x] = s[255];
}

// ------------------------------------ scan stage 2: scan block sums (1 blk) --
__global__ void k_scan2(int* __restrict__ blockSums, int* __restrict__ blockOff, int NB) {
    __shared__ int s[256];
    int tid = threadIdx.x;
    int v = (tid < NB) ? blockSums[tid] : 0;
    s[tid] = v;
    __syncthreads();
    for (int off = 1; off < 256; off <<= 1) {
        int t = (tid >= off) ? s[tid - off] : 0;
        __syncthreads();
        s[tid] += t;
        __syncthreads();
    }
    if (tid < NB) blockOff[tid] = s[tid] - v;
}

// ------- scan stage 3: rowStart = partial+blockOff; cursor=rowStart; dinv ---
__global__ void k_scan3(const int* __restrict__ partial, const int* __restrict__ blockOff,
                        const int* __restrict__ deg, int* __restrict__ rowStart,
                        int* __restrict__ cursor, float* __restrict__ dinv, int N) {
    int i = blockIdx.x * blockDim.x + threadIdx.x;
    if (i < N) {
        int rs = partial[i] + blockOff[i / SCAN_BLK];
        rowStart[i] = rs;
        cursor[i]   = rs;
        dinv[i]     = rsqrtf((float)deg[i] + 1.0f); // +1 self-loop
    }
}

// --------------------------- CSR fill, XCD-binned to kill write amplification
// Block's xcd tag = blockIdx % 8 (dispatch round-robins XCDs — perf heuristic
// only; correctness holds for any mapping since cursor atomics give unique
// positions). Each tag handles only dst in its 1/8 node range, so the dst-
// sorted edgeSrc region it writes (~0.8 MB) stays resident in one XCD L2 and
// writes back full lines.
__global__ void k_fill(const int* __restrict__ src, const int* __restrict__ dst,
                       int* __restrict__ cursor, int* __restrict__ edgeSrc,
                       int E, int N) {
    int xcd  = blockIdx.x & (NXCD - 1);
    int blk  = blockIdx.x >> 3;
    int nblk = gridDim.x >> 3;
    int lo = (int)(((long long)xcd       * N) / NXCD);
    int hi = (int)(((long long)(xcd + 1) * N) / NXCD);

    int EV = E >> 2;   // int4 groups
    bool aligned = ((E & 3) == 0);   // dst = src + E floats: 16B-aligned iff E%4==0
    if (aligned) {
        const int4* d4p = (const int4*)dst;
        const int4* s4p = (const int4*)src;
        for (int v = blk * blockDim.x + threadIdx.x; v < EV; v += nblk * blockDim.x) {
            int4 d4 = d4p[v];
            int4 s4 = s4p[v];
            if (d4.x >= lo && d4.x < hi) { int p = atomicAdd(&cursor[d4.x], 1); edgeSrc[p] = s4.x; }
            if (d4.y >= lo && d4.y < hi) { int p = atomicAdd(&cursor[d4.y], 1); edgeSrc[p] = s4.y; }
            if (d4.z >= lo && d4.z < hi) { int p = atomicAdd(&cursor[d4.z], 1); edgeSrc[p] = s4.z; }
            if (d4.w >= lo && d4.w < hi) { int p = atomicAdd(&cursor[d4.w], 1); edgeSrc[p] = s4.w; }
        }
    } else {
        for (int e = blk * blockDim.x + threadIdx.x; e < E; e += nblk * blockDim.x) {
            int d = dst[e];
            if (d >= lo && d < hi) { int p = atomicAdd(&cursor[d], 1); edgeSrc[p] = src[e]; }
        }
    }
    // remainder edges (E%4), handled once globally, unbinned (tiny)
    if (aligned) return;
}

__global__ void k_fill_tail(const int* __restrict__ src, const int* __restrict__ dst,
                            int* __restrict__ cursor, int* __restrict__ edgeSrc, int E) {
    // no-op when E%4==0; kept for generality (launched with E&3 threads max)
    int e = (E & ~3) + threadIdx.x;
    if (threadIdx.x < (E & 3)) {
        int d = dst[e];
        int p = atomicAdd(&cursor[d], 1);
        edgeSrc[p] = src[e];
    }
}

// ---------------------------------------------------- xg = dinv[i] * x[i,:] --
__global__ void k_xg(const float* __restrict__ x, const float* __restrict__ dinv,
                     float* __restrict__ xg, int N) {
    int t = blockIdx.x * blockDim.x + threadIdx.x;
    if (t < N * DIN) xg[t] = dinv[t >> 5] * x[t];
}

// ---- aggregate in input space + GEMM1 + relu + GEMM2, all fused -------------
// wave per node. lane = half*32 + f: half = edge parity, f = input feature.
// 16 edges in flight (8 accumulator slots x 2 parity lanes).
__global__ void k_agg1_gemm2(const int* __restrict__ rowStart, const int* __restrict__ deg,
                             const int* __restrict__ edgeSrc, const float* __restrict__ xg,
                             const float* __restrict__ dinv, const float* __restrict__ b1,
                             const float* __restrict__ W1, const float* __restrict__ W2,
                             float* __restrict__ g2, int N) {
    __shared__ float W1s[DIN * DH];   // 8 KB
    __shared__ float W2s[DH * DOUT];  // 4 KB
    __shared__ float hs[4][DH];
    int tid = threadIdx.x;
    for (int t = tid; t < DIN * DH; t += 256) W1s[t] = W1[t];
    for (int t = tid; t < DH * DOUT; t += 256) W2s[t] = W2[t];
    __syncthreads();

    int w = tid >> 6, lane = tid & 63;
    int f = lane & 31, half = lane >> 5;
    int node = blockIdx.x * 4 + w;   // wave-uniform

    float h = 0.f, di = 0.f;
    if (node < N) {
        di = dinv[node];
        int s = rowStart[node], c = deg[node];
        float a[8] = {0.f, 0.f, 0.f, 0.f, 0.f, 0.f, 0.f, 0.f};
        int t = 0;
        for (; t + 16 <= c; t += 16) {        // 16 edges/iter, 8 gathers in flight
            int j[8];
#pragma unroll
            for (int u = 0; u < 8; ++u) j[u] = edgeSrc[s + t + 2 * u + half];
#pragma unroll
            for (int u = 0; u < 8; ++u) a[u] += xg[(size_t)j[u] * DIN + f];
        }
        // predicated tail: up to 16 edges, all independent
#pragma unroll
        for (int u = 0; u < 8; ++u) {
            int o = t + 2 * u + half;
            if (o < c) { int j = edgeSrc[s + o]; a[u] += xg[(size_t)j * DIN + f]; }
        }

        float acc = ((a[0] + a[1]) + (a[2] + a[3])) + ((a[4] + a[5]) + (a[6] + a[7]));
        acc += __shfl_xor(acc, 32);                 // fold edge-parity halves
        acc += xg[(size_t)node * DIN + f];          // self-loop: dinv_i * x_i
        // acc now = s_i[f] in every lane (dup across halves)

        // GEMM1 via shfl broadcast: lane k computes h1[k]
        float dot = 0.f;
#pragma unroll
        for (int d = 0; d < DIN; ++d) {
            float sv = __shfl(acc, d);
            dot += sv * W1s[d * DH + lane];
        }
        h = fmaxf(di * dot + b1[lane], 0.f);        // relu(dinv_i*(s@W1)+b1)
    }
    hs[w][lane] = h;
    __syncthreads();

    if (node < N && lane < DOUT) {                  // GEMM2: g2 = dinv_i*(h1@W2)
        float dot = 0.f;
#pragma unroll
        for (int d = 0; d < DH; ++d) dot += hs[w][d] * W2s[d * DOUT + lane];
        g2[(size_t)node * DOUT + lane] = di * dot;
    }
}

// ---- layer-2 aggregate + finalize -------------------------------------------
// wave per node. lane = u*16 + k: u = edge slot (0..3), k = output feature.
// 16 edges in flight (4 slots x 4 accumulators).
__global__ void k_agg2(const int* __restrict__ rowStart, const int* __restrict__ deg,
                       const int* __restrict__ edgeSrc, const float* __restrict__ g2,
                       const float* __restrict__ dinv, const float* __restrict__ b2,
                       float* __restrict__ out, int N) {
    int tid = threadIdx.x;
    int w = tid >> 6, lane = tid & 63;
    int u = lane >> 4, k = lane & 15;
    int node = blockIdx.x * 4 + w;   // wave-uniform
    if (node >= N) return;

    int s = rowStart[node], c = deg[node];
    float a[4] = {0.f, 0.f, 0.f, 0.f};
    int t = 0;
    for (; t + 16 <= c; t += 16) {             // 16 edges/iter, 4 gathers in flight
        int j[4];
#pragma unroll
        for (int q = 0; q < 4; ++q) j[q] = edgeSrc[s + t + 4 * q + u];
#pragma unroll
        for (int q = 0; q < 4; ++q) a[q] += g2[(size_t)j[q] * DOUT + k];
    }
#pragma unroll
    for (int q = 0; q < 4; ++q) {
        int o = t + 4 * q + u;
        if (o < c) { int j = edgeSrc[s + o]; a[q] += g2[(size_t)j * DOUT + k]; }
    }

    float acc = (a[0] + a[1]) + (a[2] + a[3]);
    acc += __shfl_xor(acc, 16);                // fold 4 edge slots
    acc += __shfl_xor(acc, 32);
    acc += g2[(size_t)node * DOUT + k];        // self-loop
    if (lane < DOUT)
        out[(size_t)node * DOUT + k] = dinv[node] * acc + b2[k];
}

// ----------------------------------------------------------------------------
extern "C" void kernel_launch(void* const* d_in, const int* in_sizes, int n_in,
                              void* d_out, int out_size, void* d_ws, size_t ws_size,
                              hipStream_t stream) {
    const float* x  = (const float*)d_in[0];
    const int*   ei = (const int*)  d_in[1];
    const float* W1 = (const float*)d_in[2];
    const float* b1 = (const float*)d_in[3];
    const float* W2 = (const float*)d_in[4];
    const float* b2 = (const float*)d_in[5];
    float* out = (float*)d_out;

    int N = in_sizes[0] / DIN;
    int E = in_sizes[1] / 2;
    const int* src = ei;
    const int* dst = ei + E;
    int NB = (N + SCAN_BLK - 1) / SCAN_BLK;

    // workspace layout (4B units):
    char* p = (char*)d_ws;
    int*   deg       = (int*)p;   p += (size_t)N * 4;
    int*   partial   = (int*)p;   p += (size_t)N * 4;
    int*   rowStart  = (int*)p;   p += (size_t)N * 4;
    int*   cursor    = (int*)p;   p += (size_t)N * 4;
    int*   blockSums = (int*)p;   p += 256 * 4;
    int*   blockOff  = (int*)p;   p += 256 * 4;
    float* dinv      = (float*)p; p += (size_t)N * 4;
    int*   edgeSrc   = (int*)p;   p += (size_t)E * 4;
    float* xg        = (float*)p; p += (size_t)N * DIN * 4;
    float* g2        = (float*)p; p += (size_t)N * DOUT * 4;

    hipMemsetAsync(deg, 0, (size_t)N * 4, stream);

    k_count_deg<<<(E + 255) / 256, 256, 0, stream>>>(dst, deg, E);
    k_scan1<<<NB, 256, 0, stream>>>(deg, partial, blockSums, N);
    k_scan2<<<1, 256, 0, stream>>>(blockSums, blockOff, NB);
    k_scan3<<<(N + 255) / 256, 256, 0, stream>>>(partial, blockOff, deg,
                                                 rowStart, cursor, dinv, N);

    // XCD-binned CSR fill: 8 xcd tags x 192 stripes = 1536 blocks
    k_fill<<<NXCD * 192, 256, 0, stream>>>(src, dst, cursor, edgeSrc, E, N);
    if (E & 3)
        k_fill_tail<<<1, 64, 0, stream>>>(src, dst, cursor, edgeSrc, E);

    k_xg<<<((size_t)N * DIN + 255) / 256, 256, 0, stream>>>(x, dinv, xg, N);
    k_agg1_gemm2<<<(N + 3) / 4, 256, 0, stream>>>(rowStart, deg, edgeSrc, xg,
                                                  dinv, b1, W1, W2, g2, N);
    k_agg2<<<(N + 3) / 4, 256, 0, stream>>>(rowStart, deg, edgeSrc, g2,
                                            dinv, b2, out, N);
}

// Round 7
// 363.204 us; speedup vs baseline: 1.8105x; 1.0723x over previous
//
#include <hip/hip_runtime.h>

#define DIN  32
#define DH   64
#define DOUT 16
#define SCAN_BLK 1024   // elements per scan block; supports N <= 262144
#define NXCD 8

// ------------------------------------------------------------ degree count --
__global__ void k_count_deg(const int* __restrict__ dst, int* __restrict__ deg, int E) {
    int e = blockIdx.x * blockDim.x + threadIdx.x;
    if (e < E) atomicAdd(&deg[dst[e]], 1);
}

// ------------------------------------------------- scan stage 1: per-block --
__global__ void k_scan1(const int* __restrict__ deg, int* __restrict__ partial,
                        int* __restrict__ blockSums, int N) {
    __shared__ int s[256];
    int tid  = threadIdx.x;
    int base = blockIdx.x * SCAN_BLK + tid * 4;
    int v0 = (base + 0 < N) ? deg[base + 0] : 0;
    int v1 = (base + 1 < N) ? deg[base + 1] : 0;
    int v2 = (base + 2 < N) ? deg[base + 2] : 0;
    int v3 = (base + 3 < N) ? deg[base + 3] : 0;
    int tot = v0 + v1 + v2 + v3;
    s[tid] = tot;
    __syncthreads();
    for (int off = 1; off < 256; off <<= 1) {
        int t = (tid >= off) ? s[tid - off] : 0;
        __syncthreads();
        s[tid] += t;
        __syncthreads();
    }
    int excl = s[tid] - tot;
    if (base + 0 < N) partial[base + 0] = excl;
    if (base + 1 < N) partial[base + 1] = excl + v0;
    if (base + 2 < N) partial[base + 2] = excl + v0 + v1;
    if (base + 3 < N) partial[base + 3] = excl + v0 + v1 + v2;
    if (tid == 255) blockSums[blockIdx.x] = s[255];
}

// ------------------------------------ scan stage 2: scan block sums (1 blk) --
__global__ void k_scan2(int* __restrict__ blockSums, int* __restrict__ blockOff, int NB) {
    __shared__ int s[256];
    int tid = threadIdx.x;
    int v = (tid < NB) ? blockSums[tid] : 0;
    s[tid] = v;
    __syncthreads();
    for (int off = 1; off < 256; off <<= 1) {
        int t = (tid >= off) ? s[tid - off] : 0;
        __syncthreads();
        s[tid] += t;
        __syncthreads();
    }
    if (tid < NB) blockOff[tid] = s[tid] - v;
}

// ------- scan stage 3: rowStart = partial+blockOff; cursor=rowStart; dinv ---
__global__ void k_scan3(const int* __restrict__ partial, const int* __restrict__ blockOff,
                        const int* __restrict__ deg, int* __restrict__ rowStart,
                        int* __restrict__ cursor, float* __restrict__ dinv, int N) {
    int i = blockIdx.x * blockDim.x + threadIdx.x;
    if (i < N) {
        int rs = partial[i] + blockOff[i / SCAN_BLK];
        rowStart[i] = rs;
        cursor[i]   = rs;
        dinv[i]     = rsqrtf((float)deg[i] + 1.0f); // +1 self-loop
    }
}

// --------------------------- CSR fill, XCD-binned to kill write amplification
__global__ void k_fill(const int* __restrict__ src, const int* __restrict__ dst,
                       int* __restrict__ cursor, int* __restrict__ edgeSrc,
                       int E, int N) {
    int xcd  = blockIdx.x & (NXCD - 1);
    int blk  = blockIdx.x >> 3;
    int nblk = gridDim.x >> 3;
    int lo = (int)(((long long)xcd       * N) / NXCD);
    int hi = (int)(((long long)(xcd + 1) * N) / NXCD);

    int EV = E >> 2;   // int4 groups
    bool aligned = ((E & 3) == 0);
    if (aligned) {
        const int4* d4p = (const int4*)dst;
        const int4* s4p = (const int4*)src;
        for (int v = blk * blockDim.x + threadIdx.x; v < EV; v += nblk * blockDim.x) {
            int4 d4 = d4p[v];
            int4 s4 = s4p[v];
            if (d4.x >= lo && d4.x < hi) { int p = atomicAdd(&cursor[d4.x], 1); edgeSrc[p] = s4.x; }
            if (d4.y >= lo && d4.y < hi) { int p = atomicAdd(&cursor[d4.y], 1); edgeSrc[p] = s4.y; }
            if (d4.z >= lo && d4.z < hi) { int p = atomicAdd(&cursor[d4.z], 1); edgeSrc[p] = s4.z; }
            if (d4.w >= lo && d4.w < hi) { int p = atomicAdd(&cursor[d4.w], 1); edgeSrc[p] = s4.w; }
        }
    } else {
        for (int e = blk * blockDim.x + threadIdx.x; e < E; e += nblk * blockDim.x) {
            int d = dst[e];
            if (d >= lo && d < hi) { int p = atomicAdd(&cursor[d], 1); edgeSrc[p] = src[e]; }
        }
    }
}

// ------------------------------------------ xg = dinv[i] * x[i,:], float4 ---
__global__ void k_xg(const float4* __restrict__ x4, const float* __restrict__ dinv,
                     float4* __restrict__ xg4, int N) {
    int t = blockIdx.x * blockDim.x + threadIdx.x;
    if (t < N * 8) {                       // 8 quads per node
        float d = dinv[t >> 3];
        float4 v = x4[t];
        v.x *= d; v.y *= d; v.z *= d; v.w *= d;
        xg4[t] = v;
    }
}

// ---- aggregate in input space + GEMM1 + relu + GEMM2, all fused -------------
// wave per node. lane = es*8 + fl: es = edge slot (0..7), fl = feature quad.
// First 32 edges as ONE predicated two-stage block (indices, then gathers):
// exactly 2 latency hops per node. Rare loop for deg > 32.
__global__ void k_agg1_gemm2(const int* __restrict__ rowStart, const int* __restrict__ deg,
                             const int* __restrict__ edgeSrc, const float4* __restrict__ xg4,
                             const float* __restrict__ dinv, const float* __restrict__ b1,
                             const float* __restrict__ W1, const float* __restrict__ W2,
                             float* __restrict__ g2, int N) {
    __shared__ float W1s[DIN * DH];   // 8 KB
    __shared__ float W2s[DH * DOUT];  // 4 KB
    __shared__ float hs[4][DH];
    int tid = threadIdx.x;
    for (int t = tid; t < DIN * DH; t += 256) W1s[t] = W1[t];
    for (int t = tid; t < DH * DOUT; t += 256) W2s[t] = W2[t];
    __syncthreads();

    int w = tid >> 6, lane = tid & 63;
    int es = lane >> 3, fl = lane & 7;
    int node = blockIdx.x * 4 + w;   // wave-uniform

    float h = 0.f, di = 0.f;
    if (node < N) {
        di = dinv[node];
        int s = rowStart[node], c = deg[node];
        float4 a0 = {0,0,0,0}, a1 = {0,0,0,0}, a2 = {0,0,0,0}, a3 = {0,0,0,0};
        int j0 = 0, j1 = 0, j2 = 0, j3 = 0;
        int o0 = es, o1 = 8 + es, o2 = 16 + es, o3 = 24 + es;
        // stage 1: all index loads in flight together
        if (o0 < c) j0 = edgeSrc[s + o0];
        if (o1 < c) j1 = edgeSrc[s + o1];
        if (o2 < c) j2 = edgeSrc[s + o2];
        if (o3 < c) j3 = edgeSrc[s + o3];
        // stage 2: all payload gathers in flight together (8 edges per instr)
        if (o0 < c) a0 = xg4[(size_t)j0 * 8 + fl];
        if (o1 < c) a1 = xg4[(size_t)j1 * 8 + fl];
        if (o2 < c) a2 = xg4[(size_t)j2 * 8 + fl];
        if (o3 < c) a3 = xg4[(size_t)j3 * 8 + fl];
        // rare long tail (deg > 32)
        for (int o = 32 + es; o < c; o += 8) {
            int j = edgeSrc[s + o];
            float4 v = xg4[(size_t)j * 8 + fl];
            a0.x += v.x; a0.y += v.y; a0.z += v.z; a0.w += v.w;
        }
        float4 A;
        A.x = (a0.x + a1.x) + (a2.x + a3.x);
        A.y = (a0.y + a1.y) + (a2.y + a3.y);
        A.z = (a0.z + a1.z) + (a2.z + a3.z);
        A.w = (a0.w + a1.w) + (a2.w + a3.w);
#pragma unroll
        for (int m = 8; m <= 32; m <<= 1) {   // fold 8 edge slots
            A.x += __shfl_xor(A.x, m);
            A.y += __shfl_xor(A.y, m);
            A.z += __shfl_xor(A.z, m);
            A.w += __shfl_xor(A.w, m);
        }
        float4 sl = xg4[(size_t)node * 8 + fl];   // self-loop: dinv_i * x_i
        A.x += sl.x; A.y += sl.y; A.z += sl.z; A.w += sl.w;
        // A = s_i[4fl..4fl+3], replicated across edge slots

        // GEMM1: lane k computes h1[k]; s_i[d] from lane d>>2, comp d&3
        float dot = 0.f;
#pragma unroll
        for (int q = 0; q < 8; ++q) {
            float sx = __shfl(A.x, q), sy = __shfl(A.y, q);
            float sz = __shfl(A.z, q), sw = __shfl(A.w, q);
            dot += sx * W1s[(4 * q + 0) * DH + lane]
                 + sy * W1s[(4 * q + 1) * DH + lane]
                 + sz * W1s[(4 * q + 2) * DH + lane]
                 + sw * W1s[(4 * q + 3) * DH + lane];
        }
        h = fmaxf(di * dot + b1[lane], 0.f);      // relu(dinv_i*(s@W1)+b1)
    }
    hs[w][lane] = h;
    __syncthreads();

    if (node < N && lane < DOUT) {                // GEMM2: g2 = dinv_i*(h1@W2)
        float dot = 0.f;
#pragma unroll
        for (int d = 0; d < DH; ++d) dot += hs[w][d] * W2s[d * DOUT + lane];
        g2[(size_t)node * DOUT + lane] = di * dot;
    }
}

// ---- layer-2 aggregate + finalize -------------------------------------------
// wave per node. lane = es*4 + fl: es = edge slot (0..15), fl = feature quad.
// First 32 edges as one predicated two-stage block; rare loop beyond.
__global__ void k_agg2(const int* __restrict__ rowStart, const int* __restrict__ deg,
                       const int* __restrict__ edgeSrc, const float4* __restrict__ g2_4,
                       const float* __restrict__ dinv, const float* __restrict__ b2,
                       float4* __restrict__ out4, int N) {
    int tid = threadIdx.x;
    int w = tid >> 6, lane = tid & 63;
    int es = lane >> 2, fl = lane & 3;
    int node = blockIdx.x * 4 + w;   // wave-uniform
    if (node >= N) return;

    int s = rowStart[node], c = deg[node];
    float4 a0 = {0,0,0,0}, a1 = {0,0,0,0};
    int j0 = 0, j1 = 0;
    int o0 = es, o1 = 16 + es;
    if (o0 < c) j0 = edgeSrc[s + o0];
    if (o1 < c) j1 = edgeSrc[s + o1];
    if (o0 < c) a0 = g2_4[(size_t)j0 * 4 + fl];
    if (o1 < c) a1 = g2_4[(size_t)j1 * 4 + fl];
    for (int o = 32 + es; o < c; o += 16) {       // rare long tail
        int j = edgeSrc[s + o];
        float4 v = g2_4[(size_t)j * 4 + fl];
        a0.x += v.x; a0.y += v.y; a0.z += v.z; a0.w += v.w;
    }
    float4 A;
    A.x = a0.x + a1.x; A.y = a0.y + a1.y; A.z = a0.z + a1.z; A.w = a0.w + a1.w;
#pragma unroll
    for (int m = 4; m <= 32; m <<= 1) {           // fold 16 edge slots
        A.x += __shfl_xor(A.x, m);
        A.y += __shfl_xor(A.y, m);
        A.z += __shfl_xor(A.z, m);
        A.w += __shfl_xor(A.w, m);
    }
    float4 sl = g2_4[(size_t)node * 4 + fl];      // self-loop
    A.x += sl.x; A.y += sl.y; A.z += sl.z; A.w += sl.w;
    if (es == 0) {
        float d = dinv[node];
        const float4* b2_4 = (const float4*)b2;
        float4 bq = b2_4[fl], r;
        r.x = d * A.x + bq.x; r.y = d * A.y + bq.y;
        r.z = d * A.z + bq.z; r.w = d * A.w + bq.w;
        out4[(size_t)node * 4 + fl] = r;
    }
}

// ----------------------------------------------------------------------------
static inline size_t align16(size_t v) { return (v + 15) & ~(size_t)15; }

extern "C" void kernel_launch(void* const* d_in, const int* in_sizes, int n_in,
                              void* d_out, int out_size, void* d_ws, size_t ws_size,
                              hipStream_t stream) {
    const float* x  = (const float*)d_in[0];
    const int*   ei = (const int*)  d_in[1];
    const float* W1 = (const float*)d_in[2];
    const float* b1 = (const float*)d_in[3];
    const float* W2 = (const float*)d_in[4];
    const float* b2 = (const float*)d_in[5];

    int N = in_sizes[0] / DIN;
    int E = in_sizes[1] / 2;
    const int* src = ei;
    const int* dst = ei + E;
    int NB = (N + SCAN_BLK - 1) / SCAN_BLK;

    // workspace layout, 16B-aligned regions
    char* base = (char*)d_ws;
    size_t off = 0;
    int*   deg       = (int*)(base + off);   off = align16(off + (size_t)N * 4);
    int*   partial   = (int*)(base + off);   off = align16(off + (size_t)N * 4);
    int*   rowStart  = (int*)(base + off);   off = align16(off + (size_t)N * 4);
    int*   cursor    = (int*)(base + off);   off = align16(off + (size_t)N * 4);
    int*   blockSums = (int*)(base + off);   off = align16(off + 256 * 4);
    int*   blockOff  = (int*)(base + off);   off = align16(off + 256 * 4);
    float* dinv      = (float*)(base + off); off = align16(off + (size_t)N * 4);
    int*   edgeSrc   = (int*)(base + off);   off = align16(off + (size_t)E * 4);
    float* xg        = (float*)(base + off); off = align16(off + (size_t)N * DIN * 4);
    float* g2        = (float*)(base + off); off = align16(off + (size_t)N * DOUT * 4);

    hipMemsetAsync(deg, 0, (size_t)N * 4, stream);

    k_count_deg<<<(E + 255) / 256, 256, 0, stream>>>(dst, deg, E);
    k_scan1<<<NB, 256, 0, stream>>>(deg, partial, blockSums, N);
    k_scan2<<<1, 256, 0, stream>>>(blockSums, blockOff, NB);
    k_scan3<<<(N + 255) / 256, 256, 0, stream>>>(partial, blockOff, deg,
                                                 rowStart, cursor, dinv, N);

    k_fill<<<NXCD * 192, 256, 0, stream>>>(src, dst, cursor, edgeSrc, E, N);

    k_xg<<<((size_t)N * 8 + 255) / 256, 256, 0, stream>>>((const float4*)x, dinv,
                                                          (float4*)xg, N);
    k_agg1_gemm2<<<(N + 3) / 4, 256, 0, stream>>>(rowStart, deg, edgeSrc,
                                                  (const float4*)xg, dinv, b1,
                                                  W1, W2, g2, N);
    k_agg2<<<(N + 3) / 4, 256, 0, stream>>>(rowStart, deg, edgeSrc,
                                            (const float4*)g2, dinv, b2,
                                            (float4*)d_out, N);
}

// Round 8
// 322.739 us; speedup vs baseline: 2.0375x; 1.1254x over previous
//
#include <hip/hip_runtime.h>

#define DIN  32
#define DH   64
#define DOUT 16
#define SCAN_BLK 1024   // elements per scan block; supports N <= 262144
#define NXCD 8

// ------------------------------------------------------------ degree count --
__global__ void k_count_deg(const int* __restrict__ dst, int* __restrict__ deg, int E) {
    int e = blockIdx.x * blockDim.x + threadIdx.x;
    if (e < E) atomicAdd(&deg[dst[e]], 1);
}

// ------------------------------------------------- scan stage 1: per-block --
__global__ void k_scan1(const int* __restrict__ deg, int* __restrict__ partial,
                        int* __restrict__ blockSums, int N) {
    __shared__ int s[256];
    int tid  = threadIdx.x;
    int base = blockIdx.x * SCAN_BLK + tid * 4;
    int v0 = (base + 0 < N) ? deg[base + 0] : 0;
    int v1 = (base + 1 < N) ? deg[base + 1] : 0;
    int v2 = (base + 2 < N) ? deg[base + 2] : 0;
    int v3 = (base + 3 < N) ? deg[base + 3] : 0;
    int tot = v0 + v1 + v2 + v3;
    s[tid] = tot;
    __syncthreads();
    for (int off = 1; off < 256; off <<= 1) {
        int t = (tid >= off) ? s[tid - off] : 0;
        __syncthreads();
        s[tid] += t;
        __syncthreads();
    }
    int excl = s[tid] - tot;
    if (base + 0 < N) partial[base + 0] = excl;
    if (base + 1 < N) partial[base + 1] = excl + v0;
    if (base + 2 < N) partial[base + 2] = excl + v0 + v1;
    if (base + 3 < N) partial[base + 3] = excl + v0 + v1 + v2;
    if (tid == 255) blockSums[blockIdx.x] = s[255];
}

// ------------------------------------ scan stage 2: scan block sums (1 blk) --
__global__ void k_scan2(int* __restrict__ blockSums, int* __restrict__ blockOff, int NB) {
    __shared__ int s[256];
    int tid = threadIdx.x;
    int v = (tid < NB) ? blockSums[tid] : 0;
    s[tid] = v;
    __syncthreads();
    for (int off = 1; off < 256; off <<= 1) {
        int t = (tid >= off) ? s[tid - off] : 0;
        __syncthreads();
        s[tid] += t;
        __syncthreads();
    }
    if (tid < NB) blockOff[tid] = s[tid] - v;
}

// ------- scan stage 3: rowStart = partial+blockOff; cursor=rowStart; dinv ---
__global__ void k_scan3(const int* __restrict__ partial, const int* __restrict__ blockOff,
                        const int* __restrict__ deg, int* __restrict__ rowStart,
                        int* __restrict__ cursor, float* __restrict__ dinv, int N) {
    int i = blockIdx.x * blockDim.x + threadIdx.x;
    if (i < N) {
        int rs = partial[i] + blockOff[i / SCAN_BLK];
        rowStart[i] = rs;
        cursor[i]   = rs;
        dinv[i]     = rsqrtf((float)deg[i] + 1.0f); // +1 self-loop
    }
}

// --------------------------- CSR fill, XCD-binned to kill write amplification
__global__ void k_fill(const int* __restrict__ src, const int* __restrict__ dst,
                       int* __restrict__ cursor, int* __restrict__ edgeSrc,
                       int E, int N) {
    int xcd  = blockIdx.x & (NXCD - 1);
    int blk  = blockIdx.x >> 3;
    int nblk = gridDim.x >> 3;
    int lo = (int)(((long long)xcd       * N) / NXCD);
    int hi = (int)(((long long)(xcd + 1) * N) / NXCD);

    int EV = E >> 2;   // int4 groups
    bool aligned = ((E & 3) == 0);
    if (aligned) {
        const int4* d4p = (const int4*)dst;
        const int4* s4p = (const int4*)src;
        for (int v = blk * blockDim.x + threadIdx.x; v < EV; v += nblk * blockDim.x) {
            int4 d4 = d4p[v];
            int4 s4 = s4p[v];
            if (d4.x >= lo && d4.x < hi) { int p = atomicAdd(&cursor[d4.x], 1); edgeSrc[p] = s4.x; }
            if (d4.y >= lo && d4.y < hi) { int p = atomicAdd(&cursor[d4.y], 1); edgeSrc[p] = s4.y; }
            if (d4.z >= lo && d4.z < hi) { int p = atomicAdd(&cursor[d4.z], 1); edgeSrc[p] = s4.z; }
            if (d4.w >= lo && d4.w < hi) { int p = atomicAdd(&cursor[d4.w], 1); edgeSrc[p] = s4.w; }
        }
    } else {
        for (int e = blk * blockDim.x + threadIdx.x; e < E; e += nblk * blockDim.x) {
            int d = dst[e];
            if (d >= lo && d < hi) { int p = atomicAdd(&cursor[d], 1); edgeSrc[p] = src[e]; }
        }
    }
}

// ------------------------------------------ xg = dinv[i] * x[i,:], float4 ---
__global__ void k_xg(const float4* __restrict__ x4, const float* __restrict__ dinv,
                     float4* __restrict__ xg4, int N) {
    int t = blockIdx.x * blockDim.x + threadIdx.x;
    if (t < N * 8) {                       // 8 quads per node
        float d = dinv[t >> 3];
        float4 v = x4[t];
        v.x *= d; v.y *= d; v.z *= d; v.w *= d;
        xg4[t] = v;
    }
}

// ---- layer-1 aggregation ONLY (no GEMM): s_i = sum_j xg_j + xg_i -----------
// wave per node. lane = es*8 + fl: es = edge slot (0..7), fl = feature quad.
// First 32 edges as ONE predicated two-stage block; rare loop for deg > 32.
// LDS-pipe ops per node: just 12 shfl folds (GEMMs moved to k_gemm12).
__global__ void k_agg1(const int* __restrict__ rowStart, const int* __restrict__ deg,
                       const int* __restrict__ edgeSrc, const float4* __restrict__ xg4,
                       float4* __restrict__ s4, int N) {
    int tid = threadIdx.x;
    int w = tid >> 6, lane = tid & 63;
    int es = lane >> 3, fl = lane & 7;
    int node = blockIdx.x * 4 + w;   // wave-uniform
    if (node >= N) return;

    int s = rowStart[node], c = deg[node];
    float4 a0 = {0,0,0,0}, a1 = {0,0,0,0}, a2 = {0,0,0,0}, a3 = {0,0,0,0};
    int j0 = 0, j1 = 0, j2 = 0, j3 = 0;
    int o0 = es, o1 = 8 + es, o2 = 16 + es, o3 = 24 + es;
    // stage 1: all index loads in flight together
    if (o0 < c) j0 = edgeSrc[s + o0];
    if (o1 < c) j1 = edgeSrc[s + o1];
    if (o2 < c) j2 = edgeSrc[s + o2];
    if (o3 < c) j3 = edgeSrc[s + o3];
    // stage 2: all payload gathers in flight together (8 edges per instr)
    if (o0 < c) a0 = xg4[(size_t)j0 * 8 + fl];
    if (o1 < c) a1 = xg4[(size_t)j1 * 8 + fl];
    if (o2 < c) a2 = xg4[(size_t)j2 * 8 + fl];
    if (o3 < c) a3 = xg4[(size_t)j3 * 8 + fl];
    // rare long tail (deg > 32)
    for (int o = 32 + es; o < c; o += 8) {
        int j = edgeSrc[s + o];
        float4 v = xg4[(size_t)j * 8 + fl];
        a0.x += v.x; a0.y += v.y; a0.z += v.z; a0.w += v.w;
    }
    float4 A;
    A.x = (a0.x + a1.x) + (a2.x + a3.x);
    A.y = (a0.y + a1.y) + (a2.y + a3.y);
    A.z = (a0.z + a1.z) + (a2.z + a3.z);
    A.w = (a0.w + a1.w) + (a2.w + a3.w);
#pragma unroll
    for (int m = 8; m <= 32; m <<= 1) {   // fold 8 edge slots
        A.x += __shfl_xor(A.x, m);
        A.y += __shfl_xor(A.y, m);
        A.z += __shfl_xor(A.z, m);
        A.w += __shfl_xor(A.w, m);
    }
    if (es == 0) {
        float4 sl = xg4[(size_t)node * 8 + fl];   // self-loop: dinv_i * x_i
        A.x += sl.x; A.y += sl.y; A.z += sl.z; A.w += sl.w;
        s4[(size_t)node * 8 + fl] = A;            // 128B per node, 8 lanes
    }
}

// ---- dense per-node MLP: g2 = dinv*( relu(dinv*(s@W1)+b1) @ W2 ) -----------
// ONE NODE PER LANE. W1/W2/b1 addresses are wave-uniform -> scalar loads;
// s/h/g live in registers; zero LDS, zero shfl. Fully unrolled FMA chain.
__global__ void k_gemm12(const float* __restrict__ s, const float* __restrict__ dinv,
                         const float* __restrict__ b1, const float* __restrict__ W1,
                         const float* __restrict__ W2, float* __restrict__ g2, int N) {
    int node = blockIdx.x * blockDim.x + threadIdx.x;
    if (node >= N) return;

    float sv[DIN];
    const float4* s4 = (const float4*)s;
#pragma unroll
    for (int q = 0; q < 8; ++q) {
        float4 v = s4[(size_t)node * 8 + q];
        sv[4 * q + 0] = v.x; sv[4 * q + 1] = v.y;
        sv[4 * q + 2] = v.z; sv[4 * q + 3] = v.w;
    }

    float h[DH];
#pragma unroll
    for (int k = 0; k < DH; ++k) h[k] = 0.f;
#pragma unroll
    for (int d = 0; d < DIN; ++d) {
#pragma unroll
        for (int k = 0; k < DH; ++k) h[k] += sv[d] * W1[d * DH + k];
    }
    float di = dinv[node];
#pragma unroll
    for (int k = 0; k < DH; ++k) h[k] = fmaxf(di * h[k] + b1[k], 0.f);

    float g[DOUT];
#pragma unroll
    for (int k = 0; k < DOUT; ++k) g[k] = 0.f;
#pragma unroll
    for (int d = 0; d < DH; ++d) {
#pragma unroll
        for (int k = 0; k < DOUT; ++k) g[k] += h[d] * W2[d * DOUT + k];
    }

    float4* g2_4 = (float4*)g2;
#pragma unroll
    for (int q = 0; q < 4; ++q) {
        float4 r;
        r.x = di * g[4 * q + 0]; r.y = di * g[4 * q + 1];
        r.z = di * g[4 * q + 2]; r.w = di * g[4 * q + 3];
        g2_4[(size_t)node * 4 + q] = r;
    }
}

// ---- layer-2 aggregate + finalize -------------------------------------------
// wave per node. lane = es*4 + fl: es = edge slot (0..15), fl = feature quad.
__global__ void k_agg2(const int* __restrict__ rowStart, const int* __restrict__ deg,
                       const int* __restrict__ edgeSrc, const float4* __restrict__ g2_4,
                       const float* __restrict__ dinv, const float* __restrict__ b2,
                       float4* __restrict__ out4, int N) {
    int tid = threadIdx.x;
    int w = tid >> 6, lane = tid & 63;
    int es = lane >> 2, fl = lane & 3;
    int node = blockIdx.x * 4 + w;   // wave-uniform
    if (node >= N) return;

    int s = rowStart[node], c = deg[node];
    float4 a0 = {0,0,0,0}, a1 = {0,0,0,0};
    int j0 = 0, j1 = 0;
    int o0 = es, o1 = 16 + es;
    if (o0 < c) j0 = edgeSrc[s + o0];
    if (o1 < c) j1 = edgeSrc[s + o1];
    if (o0 < c) a0 = g2_4[(size_t)j0 * 4 + fl];
    if (o1 < c) a1 = g2_4[(size_t)j1 * 4 + fl];
    for (int o = 32 + es; o < c; o += 16) {       // rare long tail
        int j = edgeSrc[s + o];
        float4 v = g2_4[(size_t)j * 4 + fl];
        a0.x += v.x; a0.y += v.y; a0.z += v.z; a0.w += v.w;
    }
    float4 A;
    A.x = a0.x + a1.x; A.y = a0.y + a1.y; A.z = a0.z + a1.z; A.w = a0.w + a1.w;
#pragma unroll
    for (int m = 4; m <= 32; m <<= 1) {           // fold 16 edge slots
        A.x += __shfl_xor(A.x, m);
        A.y += __shfl_xor(A.y, m);
        A.z += __shfl_xor(A.z, m);
        A.w += __shfl_xor(A.w, m);
    }
    if (es == 0) {
        float4 sl = g2_4[(size_t)node * 4 + fl];  // self-loop
        A.x += sl.x; A.y += sl.y; A.z += sl.z; A.w += sl.w;
        float d = dinv[node];
        const float4* b2_4 = (const float4*)b2;
        float4 bq = b2_4[fl], r;
        r.x = d * A.x + bq.x; r.y = d * A.y + bq.y;
        r.z = d * A.z + bq.z; r.w = d * A.w + bq.w;
        out4[(size_t)node * 4 + fl] = r;
    }
}

// ----------------------------------------------------------------------------
static inline size_t align16(size_t v) { return (v + 15) & ~(size_t)15; }

extern "C" void kernel_launch(void* const* d_in, const int* in_sizes, int n_in,
                              void* d_out, int out_size, void* d_ws, size_t ws_size,
                              hipStream_t stream) {
    const float* x  = (const float*)d_in[0];
    const int*   ei = (const int*)  d_in[1];
    const float* W1 = (const float*)d_in[2];
    const float* b1 = (const float*)d_in[3];
    const float* W2 = (const float*)d_in[4];
    const float* b2 = (const float*)d_in[5];

    int N = in_sizes[0] / DIN;
    int E = in_sizes[1] / 2;
    const int* src = ei;
    const int* dst = ei + E;
    int NB = (N + SCAN_BLK - 1) / SCAN_BLK;

    // workspace layout, 16B-aligned regions
    char* base = (char*)d_ws;
    size_t off = 0;
    int*   deg       = (int*)(base + off);   off = align16(off + (size_t)N * 4);
    int*   partial   = (int*)(base + off);   off = align16(off + (size_t)N * 4);
    int*   rowStart  = (int*)(base + off);   off = align16(off + (size_t)N * 4);
    int*   cursor    = (int*)(base + off);   off = align16(off + (size_t)N * 4);
    int*   blockSums = (int*)(base + off);   off = align16(off + 256 * 4);
    int*   blockOff  = (int*)(base + off);   off = align16(off + 256 * 4);
    float* dinv      = (float*)(base + off); off = align16(off + (size_t)N * 4);
    int*   edgeSrc   = (int*)(base + off);   off = align16(off + (size_t)E * 4);
    float* xg        = (float*)(base + off); off = align16(off + (size_t)N * DIN * 4);
    float* sagg      = (float*)(base + off); off = align16(off + (size_t)N * DIN * 4);
    float* g2        = (float*)(base + off); off = align16(off + (size_t)N * DOUT * 4);

    hipMemsetAsync(deg, 0, (size_t)N * 4, stream);

    k_count_deg<<<(E + 255) / 256, 256, 0, stream>>>(dst, deg, E);
    k_scan1<<<NB, 256, 0, stream>>>(deg, partial, blockSums, N);
    k_scan2<<<1, 256, 0, stream>>>(blockSums, blockOff, NB);
    k_scan3<<<(N + 255) / 256, 256, 0, stream>>>(partial, blockOff, deg,
                                                 rowStart, cursor, dinv, N);

    k_fill<<<NXCD * 192, 256, 0, stream>>>(src, dst, cursor, edgeSrc, E, N);

    k_xg<<<((size_t)N * 8 + 255) / 256, 256, 0, stream>>>((const float4*)x, dinv,
                                                          (float4*)xg, N);
    k_agg1<<<(N + 3) / 4, 256, 0, stream>>>(rowStart, deg, edgeSrc,
                                            (const float4*)xg, (float4*)sagg, N);
    k_gemm12<<<(N + 255) / 256, 256, 0, stream>>>(sagg, dinv, b1, W1, W2, g2, N);
    k_agg2<<<(N + 3) / 4, 256, 0, stream>>>(rowStart, deg, edgeSrc,
                                            (const float4*)g2, dinv, b2,
                                            (float4*)d_out, N);
}